// Round 5
// baseline (40.578 us; speedup 1.0000x reference)
//
#include <hip/hip_runtime.h>
#include <hip/hip_bf16.h>

// Problem constants (match reference setup_inputs)
constexpr int B       = 64;
constexpr int S       = 4096;
constexpr int D       = 128;
constexpr int NC      = 64;    // N_CELLS
constexpr int DTH     = 63;    // d_theta = NC - 1
constexpr int NSTEPS  = 50;
constexpr int SPLIT   = 16;    // S-chunks per batch for the reduction
constexpr int SC      = S / SPLIT;  // 256 rows per chunk

// ---------------------------------------------------------------------------
// Stage 1: partial column sums of input_seq over S.  (R1-proven structure.)
//   in   : (B, S, D) f32
//   part : (B*SPLIT, D) f32
// 1024 blocks x 256 threads; float4 loads; each wave instruction covers
// 1 KiB contiguous. BW-bound at ~6.5-7 TB/s.
// ---------------------------------------------------------------------------
__global__ __launch_bounds__(256) void cpab_reduce(const float* __restrict__ in,
                                                   float* __restrict__ part) {
    const int blk   = blockIdx.x;          // 0 .. B*SPLIT-1
    const int b     = blk / SPLIT;
    const int chunk = blk % SPLIT;
    const int t     = threadIdx.x;         // 0..255
    const int d4    = t & 31;              // which float4 of the 32 per row
    const int srow  = t >> 5;              // 0..7

    const float4* base = reinterpret_cast<const float4*>(
        in + (size_t)b * S * D + (size_t)chunk * SC * D);

    float4 acc = make_float4(0.f, 0.f, 0.f, 0.f);
    for (int s = srow; s < SC; s += 8) {
        float4 v = base[s * 32 + d4];
        acc.x += v.x; acc.y += v.y; acc.z += v.z; acc.w += v.w;
    }

    __shared__ float4 sm[256];
    sm[t] = acc;
    __syncthreads();

    if (t < 32) {
        float4 a = sm[t];
        #pragma unroll
        for (int r = 1; r < 8; ++r) {
            float4 v = sm[r * 32 + t];
            a.x += v.x; a.y += v.y; a.z += v.z; a.w += v.w;
        }
        reinterpret_cast<float4*>(part + (size_t)(b * SPLIT + chunk) * D)[d4] = a;
    }
}

// ---------------------------------------------------------------------------
// Stage 2+3 in ONE dispatch, one self-contained block per batch:
//   fold partials -> mean -> theta -> A   (bit-identical to the proven
//   theta kernel: same serial loops, same order)
//   then integrate this batch's 4096 grid points (4 points per thread,
//   4 independent Euler chains -> ILP over the LDS-gather latency).
// No cross-block dependencies: dispatch-boundary coherence only.
// ---------------------------------------------------------------------------
__global__ __launch_bounds__(1024) void cpab_batch(const float* __restrict__ part,
                                                   const float* __restrict__ W,
                                                   const float* __restrict__ bloc,
                                                   const float* __restrict__ basis,
                                                   float* __restrict__ out) {
    const int b = blockIdx.x;   // 0..B-1
    const int t = threadIdx.x;  // 0..1023

    __shared__ float s_mean[D];
    __shared__ float s_theta[64];   // DTH=63 (+pad)
    __shared__ float s_ab[128];

    // ---- fold partials -> mean (t < 128) ----------------------------------
    if (t < D) {
        float tot = 0.f;
        #pragma unroll
        for (int c = 0; c < SPLIT; ++c)
            tot += part[(size_t)(b * SPLIT + c) * D + t];
        s_mean[t] = tot * (1.0f / (float)S);
    }
    __syncthreads();

    // ---- theta (t < 63, serial d-loop: proven numerics) -------------------
    if (t < DTH) {
        float th = bloc[t];
        for (int d = 0; d < D; ++d)
            th += s_mean[d] * W[d * DTH + t];
        s_theta[t] = th;
    }
    __syncthreads();

    // ---- A = theta @ basis^T (t < 128) ------------------------------------
    if (t < 128) {
        float acc = 0.f;
        for (int j = 0; j < DTH; ++j)
            acc += s_theta[j] * basis[t * DTH + j];
        s_ab[t] = acc;
    }
    __syncthreads();

    // ---- integrate: 4 points per thread, independent chains ---------------
    const float dt = 1.0f / (float)NSTEPS;
    float x0 = (float)(t)          * (1.0f / (float)(S - 1));
    float x1 = (float)(t + 1024)   * (1.0f / (float)(S - 1));
    float x2 = (float)(t + 2048)   * (1.0f / (float)(S - 1));
    float x3 = (float)(t + 3072)   * (1.0f / (float)(S - 1));

    #pragma unroll
    for (int it = 0; it < NSTEPS; ++it) {
        int c0 = (int)(x0 * (float)NC);
        int c1 = (int)(x1 * (float)NC);
        int c2 = (int)(x2 * (float)NC);
        int c3 = (int)(x3 * (float)NC);
        c0 = c0 < 0 ? 0 : (c0 > NC - 1 ? NC - 1 : c0);
        c1 = c1 < 0 ? 0 : (c1 > NC - 1 ? NC - 1 : c1);
        c2 = c2 < 0 ? 0 : (c2 > NC - 1 ? NC - 1 : c2);
        c3 = c3 < 0 ? 0 : (c3 > NC - 1 ? NC - 1 : c3);
        float a0 = s_ab[2 * c0], b0 = s_ab[2 * c0 + 1];
        float a1 = s_ab[2 * c1], b1 = s_ab[2 * c1 + 1];
        float a2 = s_ab[2 * c2], b2 = s_ab[2 * c2 + 1];
        float a3 = s_ab[2 * c3], b3 = s_ab[2 * c3 + 1];
        x0 = x0 + (a0 * x0 + b0) * dt;
        x1 = x1 + (a1 * x1 + b1) * dt;
        x2 = x2 + (a2 * x2 + b2) * dt;
        x3 = x3 + (a3 * x3 + b3) * dt;
    }

    float* ob = out + (size_t)b * S;
    ob[t]        = x0;
    ob[t + 1024] = x1;
    ob[t + 2048] = x2;
    ob[t + 3072] = x3;
}

extern "C" void kernel_launch(void* const* d_in, const int* in_sizes, int n_in,
                              void* d_out, int out_size, void* d_ws, size_t ws_size,
                              hipStream_t stream) {
    const float* in_seq = (const float*)d_in[0];  // (B, S, D)
    const float* W_loc  = (const float*)d_in[1];  // (D, DTH)
    const float* b_loc  = (const float*)d_in[2];  // (DTH,)
    const float* basis  = (const float*)d_in[3];  // (2*NC, DTH)
    float*       out    = (float*)d_out;          // (B, S)

    // Workspace: partials (B*SPLIT*D = 512 KiB) in d_ws.
    float* part = (float*)d_ws;

    cpab_reduce<<<B * SPLIT, 256, 0, stream>>>(in_seq, part);
    cpab_batch<<<B, 1024, 0, stream>>>(part, W_loc, b_loc, basis, out);
}

// Round 6
// 35.947 us; speedup vs baseline: 1.1288x; 1.1288x over previous
//
#include <hip/hip_runtime.h>
#include <hip/hip_bf16.h>

// Problem constants (match reference setup_inputs)
constexpr int B       = 64;
constexpr int S       = 4096;
constexpr int D       = 128;
constexpr int NC      = 64;    // N_CELLS
constexpr int DTH     = 63;    // d_theta = NC - 1
constexpr int NSTEPS  = 50;
constexpr int SPLIT   = 16;    // S-chunks per batch
constexpr int SC      = S / SPLIT;  // 256 rows per chunk

// thc layout: (B*SPLIT, 64) — padded to 64 for alignment. 256 KiB in d_ws.
constexpr int THC_LD  = 64;

// ---------------------------------------------------------------------------
// K1: per-chunk column sums (R1-proven BW-bound core) -> immediately apply
// W to produce this chunk's theta CONTRIBUTION (63 floats):
//   thc[b,chunk,j] = sum_d colsum_chunk[d] * W[d,j]
// Only 64 KB of contributions are written; no partial-sum buffer, and the
// separate theta dispatch disappears.
// ---------------------------------------------------------------------------
__global__ __launch_bounds__(256) void cpab_reduce_theta(const float* __restrict__ in,
                                                         const float* __restrict__ W,
                                                         float* __restrict__ thc) {
    const int blk   = blockIdx.x;          // 0 .. B*SPLIT-1
    const int b     = blk / SPLIT;
    const int chunk = blk % SPLIT;
    const int t     = threadIdx.x;         // 0..255
    const int d4    = t & 31;              // which float4 of the 32 per row
    const int srow  = t >> 5;              // 0..7

    const float4* base = reinterpret_cast<const float4*>(
        in + (size_t)b * S * D + (size_t)chunk * SC * D);

    float4 acc = make_float4(0.f, 0.f, 0.f, 0.f);
    for (int s = srow; s < SC; s += 8) {
        float4 v = base[s * 32 + d4];
        acc.x += v.x; acc.y += v.y; acc.z += v.z; acc.w += v.w;
    }

    __shared__ float4 sm[256];
    __shared__ float  s_col[D];
    sm[t] = acc;
    __syncthreads();

    if (t < 32) {
        float4 a = sm[t];
        #pragma unroll
        for (int r = 1; r < 8; ++r) {
            float4 v = sm[r * 32 + t];
            a.x += v.x; a.y += v.y; a.z += v.z; a.w += v.w;
        }
        reinterpret_cast<float4*>(s_col)[t] = a;
    }
    __syncthreads();

    // theta contribution: 63 threads x 128 MACs (s_col broadcast reads,
    // W reads coalesced across t). ~300 ns tail, overlapped across blocks.
    if (t < DTH) {
        float th = 0.f;
        #pragma unroll 8
        for (int d = 0; d < D; ++d)
            th += s_col[d] * W[d * DTH + t];
        thc[(size_t)(b * SPLIT + chunk) * THC_LD + t] = th;
    }
}

// ---------------------------------------------------------------------------
// K2: per-block (cheap, deterministic): fold 16 theta contributions ->
// theta -> ab = theta @ basis^T, then integrate 256 grid points (R1-proven
// warp body). 1024 blocks x 256 threads.
// ---------------------------------------------------------------------------
__global__ __launch_bounds__(256) void cpab_warp2(const float* __restrict__ thc,
                                                  const float* __restrict__ bloc,
                                                  const float* __restrict__ basis,
                                                  float* __restrict__ out) {
    const int blk   = blockIdx.x;          // B * (S/256)
    const int b     = blk >> 4;
    const int chunk = blk & 15;
    const int t     = threadIdx.x;

    __shared__ float s_theta[64];          // DTH=63 (+pad)
    __shared__ float s_ab[128];

    if (t < DTH) {
        float acc = 0.f;
        #pragma unroll
        for (int c = 0; c < SPLIT; ++c)
            acc += thc[(size_t)(b * SPLIT + c) * THC_LD + t];
        s_theta[t] = bloc[t] + acc * (1.0f / (float)S);
    }
    __syncthreads();

    if (t < 128) {
        float acc = 0.f;
        for (int j = 0; j < DTH; ++j)
            acc += s_theta[j] * basis[t * DTH + j];
        s_ab[t] = acc;
    }
    __syncthreads();

    const int s = chunk * 256 + t;
    float x = (float)s * (1.0f / (float)(S - 1));
    const float dt = 1.0f / (float)NSTEPS;

    #pragma unroll
    for (int it = 0; it < NSTEPS; ++it) {
        int c = (int)(x * (float)NC);          // trunc toward zero == astype(int32)
        c = c < 0 ? 0 : (c > NC - 1 ? NC - 1 : c);
        float a  = s_ab[2 * c];
        float bb = s_ab[2 * c + 1];
        x = x + (a * x + bb) * dt;
    }

    out[(size_t)b * S + s] = x;
}

extern "C" void kernel_launch(void* const* d_in, const int* in_sizes, int n_in,
                              void* d_out, int out_size, void* d_ws, size_t ws_size,
                              hipStream_t stream) {
    const float* in_seq = (const float*)d_in[0];  // (B, S, D)
    const float* W_loc  = (const float*)d_in[1];  // (D, DTH)
    const float* b_loc  = (const float*)d_in[2];  // (DTH,)
    const float* basis  = (const float*)d_in[3];  // (2*NC, DTH)
    float*       out    = (float*)d_out;          // (B, S)

    // Workspace: theta contributions (B*SPLIT*64 floats = 256 KiB).
    float* thc = (float*)d_ws;

    cpab_reduce_theta<<<B * SPLIT, 256, 0, stream>>>(in_seq, W_loc, thc);
    cpab_warp2<<<B * (S / 256), 256, 0, stream>>>(thc, b_loc, basis, out);
}

// Round 8
// 35.544 us; speedup vs baseline: 1.1416x; 1.0114x over previous
//
#include <hip/hip_runtime.h>
#include <hip/hip_bf16.h>

// Problem constants (match reference setup_inputs)
constexpr int B       = 64;
constexpr int S       = 4096;
constexpr int D       = 128;
constexpr int NC      = 64;    // N_CELLS
constexpr int DTH     = 63;    // d_theta = NC - 1
constexpr int NSTEPS  = 50;
constexpr int SPLIT   = 16;    // S-chunks per batch
constexpr int SC      = S / SPLIT;  // 256 rows per chunk

// thc layout: (B*SPLIT, 64) — padded to 64 for alignment. 256 KiB in d_ws.
constexpr int THC_LD  = 64;

// Native clang vector type: __builtin_nontemporal_load requires a pointer to
// a scalar or native vector type (HIP_vector_type structs are rejected).
typedef float floatx4 __attribute__((ext_vector_type(4)));

// ---------------------------------------------------------------------------
// K1: per-chunk column sums -> apply W -> per-chunk theta contribution.
// Input stream uses NON-TEMPORAL loads (global_load_dwordx4 ... nt): the
// 128 MiB input is single-use-per-replay, so don't let it thrash L1/L2.
// ---------------------------------------------------------------------------
__global__ __launch_bounds__(256) void cpab_reduce_theta(const float* __restrict__ in,
                                                         const float* __restrict__ W,
                                                         float* __restrict__ thc) {
    const int blk   = blockIdx.x;          // 0 .. B*SPLIT-1
    const int b     = blk / SPLIT;
    const int chunk = blk % SPLIT;
    const int t     = threadIdx.x;         // 0..255
    const int d4    = t & 31;              // which float4 of the 32 per row
    const int srow  = t >> 5;              // 0..7

    const floatx4* base = reinterpret_cast<const floatx4*>(
        in + (size_t)b * S * D + (size_t)chunk * SC * D);

    floatx4 acc = (floatx4){0.f, 0.f, 0.f, 0.f};
    for (int s = srow; s < SC; s += 8) {
        floatx4 v = __builtin_nontemporal_load(&base[s * 32 + d4]);
        acc += v;
    }

    __shared__ floatx4 sm[256];
    __shared__ float   s_col[D];
    sm[t] = acc;
    __syncthreads();

    if (t < 32) {
        floatx4 a = sm[t];
        #pragma unroll
        for (int r = 1; r < 8; ++r)
            a += sm[r * 32 + t];
        reinterpret_cast<floatx4*>(s_col)[t] = a;
    }
    __syncthreads();

    // theta contribution: 63 threads x 128 MACs (s_col broadcast reads,
    // W reads coalesced across t and L2-resident).
    if (t < DTH) {
        float th = 0.f;
        #pragma unroll 8
        for (int d = 0; d < D; ++d)
            th += s_col[d] * W[d * DTH + t];
        thc[(size_t)(b * SPLIT + chunk) * THC_LD + t] = th;
    }
}

// ---------------------------------------------------------------------------
// K2: fold 16 theta contributions -> theta -> ab = theta @ basis^T,
// then integrate 256 grid points. 1024 blocks x 256 threads. (R6-proven.)
// ---------------------------------------------------------------------------
__global__ __launch_bounds__(256) void cpab_warp2(const float* __restrict__ thc,
                                                  const float* __restrict__ bloc,
                                                  const float* __restrict__ basis,
                                                  float* __restrict__ out) {
    const int blk   = blockIdx.x;          // B * (S/256)
    const int b     = blk >> 4;
    const int chunk = blk & 15;
    const int t     = threadIdx.x;

    __shared__ float s_theta[64];          // DTH=63 (+pad)
    __shared__ float s_ab[128];

    if (t < DTH) {
        float acc = 0.f;
        #pragma unroll
        for (int c = 0; c < SPLIT; ++c)
            acc += thc[(size_t)(b * SPLIT + c) * THC_LD + t];
        s_theta[t] = bloc[t] + acc * (1.0f / (float)S);
    }
    __syncthreads();

    if (t < 128) {
        float acc = 0.f;
        for (int j = 0; j < DTH; ++j)
            acc += s_theta[j] * basis[t * DTH + j];
        s_ab[t] = acc;
    }
    __syncthreads();

    const int s = chunk * 256 + t;
    float x = (float)s * (1.0f / (float)(S - 1));
    const float dt = 1.0f / (float)NSTEPS;

    #pragma unroll
    for (int it = 0; it < NSTEPS; ++it) {
        int c = (int)(x * (float)NC);          // trunc toward zero == astype(int32)
        c = c < 0 ? 0 : (c > NC - 1 ? NC - 1 : c);
        float a  = s_ab[2 * c];
        float bb = s_ab[2 * c + 1];
        x = x + (a * x + bb) * dt;
    }

    out[(size_t)b * S + s] = x;
}

extern "C" void kernel_launch(void* const* d_in, const int* in_sizes, int n_in,
                              void* d_out, int out_size, void* d_ws, size_t ws_size,
                              hipStream_t stream) {
    const float* in_seq = (const float*)d_in[0];  // (B, S, D)
    const float* W_loc  = (const float*)d_in[1];  // (D, DTH)
    const float* b_loc  = (const float*)d_in[2];  // (DTH,)
    const float* basis  = (const float*)d_in[3];  // (2*NC, DTH)
    float*       out    = (float*)d_out;          // (B, S)

    // Workspace: theta contributions (B*SPLIT*64 floats = 256 KiB).
    float* thc = (float*)d_ws;

    cpab_reduce_theta<<<B * SPLIT, 256, 0, stream>>>(in_seq, W_loc, thc);
    cpab_warp2<<<B * (S / 256), 256, 0, stream>>>(thc, b_loc, basis, out);
}